// Round 7
// baseline (1086.393 us; speedup 1.0000x reference)
//
#include <hip/hip_runtime.h>
#include <math.h>

#define N_SAMP 512
#define C_IN   12
#define L_IN   8192
#define NDIL   6
#define NFILT  30
#define NFEAT  180
#define NCHUNK 4
#define CHUNK  (L_IN / NCHUNK)   // 2048
#define EPSV   1e-5f

#define HALO   160               // 5 * max dilation(32)
#define TLC    512               // positions per stage tile
#define LWC    (TLC + 2*HALO)    // 832 rows
#define TILEB  (LWC * 16)        // 13312 bytes per (hi|lo) LDS part

// ws layout: [0, WF_OFF) float partials; then wc, wd (i8 frag tables), bias
#define WF_OFF (3 * N_SAMP * NCHUNK * NFILT * 2)   // 368640 floats
#define WTAB_B (NDIL * 3 * 64 * 16)                // 18432 bytes per table

typedef __attribute__((ext_vector_type(4))) int i32x4;

// XOR quad-swizzle: bijective involution on 16B cells, varies under row
// steps of 8/16/32 so all dilation strides spread across bank quads.
__device__ __forceinline__ int swz(int r) {
    return (r << 4) ^ (((r >> 3) & 7) << 4);
}

// ---------------------------------------------------------------------------
// Build i8 B-fragment tables (C = hi7, D = lo7 of W = round(w*8192)) in MFMA
// lane layout, plus f32 bias table. k = q*16 + e -> (tap = mf*4+q, c = e).
// tap 11 (mf=2,q=3) is zero-weighted padding.
// ---------------------------------------------------------------------------
__global__ __launch_bounds__(256)
void build_wb(const float* __restrict__ W7, const float* __restrict__ W9,
              const float* __restrict__ W11, const float* __restrict__ b7,
              const float* __restrict__ b9, const float* __restrict__ b11,
              signed char* __restrict__ wc, signed char* __restrict__ wd,
              float* __restrict__ bias_tab)
{
    const int t = blockIdx.x * 256 + threadIdx.x;
    if (t < NDIL * 3 * 64) {
        const int j    = t / 192;
        const int mf   = (t / 64) % 3;
        const int lane = t % 64;
        const int col  = lane & 15;
        const int q    = lane >> 4;
        const int tap  = mf * 4 + q;
#pragma unroll
        for (int e = 0; e < 16; ++e) {
            float v = 0.0f;
            if (col < 15 && tap <= 10 && e < 12) {
                const int toff = tap - 5;
                if (col < 5) {
                    if (toff >= -3 && toff <= 3)
                        v = W7[((j * 5 + col) * 12 + e) * 7 + toff + 3];
                } else if (col < 10) {
                    if (toff >= -4 && toff <= 4)
                        v = W9[((j * 5 + col - 5) * 12 + e) * 9 + toff + 4];
                } else {
                    v = W11[((j * 5 + col - 10) * 12 + e) * 11 + toff + 5];
                }
            }
            const int W  = __float2int_rn(v * 8192.0f);
            const int C8 = (W + 64) >> 7;       // in [-64, 64]
            const int D8 = W - (C8 << 7);       // in [-64, 63]
            wc[(size_t)t * 16 + e] = (signed char)C8;
            wd[(size_t)t * 16 + e] = (signed char)D8;
        }
    } else if (t < NDIL * 3 * 64 + 96) {
        const int i = t - NDIL * 3 * 64;
        const int j = i / 16, s = i % 16;
        float b = 0.0f;
        if (s < 5)       b = b7 [j * 5 + s];
        else if (s < 10) b = b9 [j * 5 + s - 5];
        else if (s < 15) b = b11[j * 5 + s - 10];
        bias_tab[j * 16 + s] = b;
    }
}

// ---------------------------------------------------------------------------
// i8 MFMA conv, exact fixed-point 3-term split:
//   X = round(x*2048) = 128A + B;  W = round(w*8192) = 128C + D
//   x*w*2^24 ~= 16384*(A.C) + 128*(A.D + B.C)      [B.D dropped, sigma~9e-4]
// One (sample, 2048-chunk) per block, all 6 dilations, all 3 kernel sizes.
// Per 16-pos tile per dilation: 6 ds_read_b128 + 9 MFMA (K=64 = 4 taps x 16c).
// ---------------------------------------------------------------------------
__global__ __launch_bounds__(256, 4)
void rocket_conv_i8(const float* __restrict__ x,
                    const signed char* __restrict__ wc,
                    const signed char* __restrict__ wd,
                    const float* __restrict__ bias_tab,
                    float* __restrict__ ws)
{
    __shared__ __align__(16) signed char xq[2][TILEB];   // hi | lo, 26624 B

    const int ch  = blockIdx.x;
    const int n   = blockIdx.y;
    const int tid = threadIdx.x;
    const int lane = tid & 63, wv = tid >> 6;
    const int row_l = lane & 15, q = lane >> 4;
    const float* __restrict__ xrow = x + (size_t)n * C_IN * L_IN;
    const i32x4* __restrict__ wcv = (const i32x4*)wc;
    const i32x4* __restrict__ wdv = (const i32x4*)wd;

    float bcol[NDIL];
#pragma unroll
    for (int j = 0; j < NDIL; ++j) bcol[j] = bias_tab[j * 16 + row_l];

    float cnt[NDIL], mx[NDIL];
#pragma unroll
    for (int j = 0; j < NDIL; ++j) { cnt[j] = 0.0f; mx[j] = -INFINITY; }

    const int c0 = ch * CHUNK;
#pragma unroll 1
    for (int st = 0; st < CHUNK / TLC; ++st) {
        const int t0 = c0 + st * TLC;
        __syncthreads();
        // ---- stage: quantize x to (A,B) i8 pairs, swizzled 16B rows ----
#pragma unroll 1
        for (int r = tid; r < LWC; r += 256) {
            const int g = t0 - HALO + r;
            int h[4] = {0, 0, 0, 0}, l[4] = {0, 0, 0, 0};
            if ((unsigned)g < (unsigned)L_IN) {
#pragma unroll
                for (int c = 0; c < 12; ++c) {
                    const float xv = xrow[c * L_IN + g];
                    const int X  = __float2int_rn(xv * 2048.0f);
                    const int A8 = (X + 64) >> 7;
                    const int B8 = X - (A8 << 7);
                    h[c >> 2] |= (A8 & 255) << ((c & 3) * 8);
                    l[c >> 2] |= (B8 & 255) << ((c & 3) * 8);
                }
            }
            const int cell = swz(r);
            *(i32x4*)&xq[0][cell] = (i32x4){h[0], h[1], h[2], h[3]};
            *(i32x4*)&xq[1][cell] = (i32x4){l[0], l[1], l[2], l[3]};
        }
        __syncthreads();

        // ---- compute: 6 dilations x 8 pos-tiles/wave ----
#pragma unroll
        for (int j = 0; j < NDIL; ++j) {
            const int d = 1 << j;
            i32x4 C0 = wcv[(j * 3 + 0) * 64 + lane];
            i32x4 C1 = wcv[(j * 3 + 1) * 64 + lane];
            i32x4 C2 = wcv[(j * 3 + 2) * 64 + lane];
            i32x4 D0 = wdv[(j * 3 + 0) * 64 + lane];
            i32x4 D1 = wdv[(j * 3 + 1) * 64 + lane];
            i32x4 D2 = wdv[(j * 3 + 2) * 64 + lane];
            // per-lane A row offsets for taps {q, q+4, q+8} (tap 11 -> 0)
            const int r0 = HALO + wv * 128 + row_l + (q - 5) * d;
            const int r1 = HALO + wv * 128 + row_l + (q - 1) * d;
            const int r2 = HALO + wv * 128 + row_l +
                           ((q == 3) ? 0 : (q + 3) * d);
            const float bj = bcol[j];
#pragma unroll
            for (int t = 0; t < 8; ++t) {
                const int cell0 = swz(r0 + 16 * t);
                const int cell1 = swz(r1 + 16 * t);
                const int cell2 = swz(r2 + 16 * t);
                i32x4 acc1 = {0, 0, 0, 0};
                i32x4 acc2 = {0, 0, 0, 0};
                {
                    i32x4 ah = *(const i32x4*)&xq[0][cell0];
                    i32x4 al = *(const i32x4*)&xq[1][cell0];
                    acc1 = __builtin_amdgcn_mfma_i32_16x16x64_i8(ah, C0, acc1, 0, 0, 0);
                    acc2 = __builtin_amdgcn_mfma_i32_16x16x64_i8(ah, D0, acc2, 0, 0, 0);
                    acc2 = __builtin_amdgcn_mfma_i32_16x16x64_i8(al, C0, acc2, 0, 0, 0);
                }
                {
                    i32x4 ah = *(const i32x4*)&xq[0][cell1];
                    i32x4 al = *(const i32x4*)&xq[1][cell1];
                    acc1 = __builtin_amdgcn_mfma_i32_16x16x64_i8(ah, C1, acc1, 0, 0, 0);
                    acc2 = __builtin_amdgcn_mfma_i32_16x16x64_i8(ah, D1, acc2, 0, 0, 0);
                    acc2 = __builtin_amdgcn_mfma_i32_16x16x64_i8(al, C1, acc2, 0, 0, 0);
                }
                {
                    i32x4 ah = *(const i32x4*)&xq[0][cell2];
                    i32x4 al = *(const i32x4*)&xq[1][cell2];
                    acc1 = __builtin_amdgcn_mfma_i32_16x16x64_i8(ah, C2, acc1, 0, 0, 0);
                    acc2 = __builtin_amdgcn_mfma_i32_16x16x64_i8(ah, D2, acc2, 0, 0, 0);
                    acc2 = __builtin_amdgcn_mfma_i32_16x16x64_i8(al, C2, acc2, 0, 0, 0);
                }
#pragma unroll
                for (int i = 0; i < 4; ++i) {
                    const float out = bj
                        + (float)acc1[i] * 0.0009765625f      // 16384 / 2^24
                        + (float)acc2[i] * 7.62939453125e-6f; // 128 / 2^24
                    cnt[j] += (out > 0.0f) ? 1.0f : 0.0f;
                    mx[j]   = fmaxf(mx[j], out);
                }
            }
        }
    }

    // ---- reduce: lanes {s, s+16, s+32, s+48} hold same filter col s ----
    __syncthreads();                       // xq dead; alias reduction scratch
    float* redc = (float*)&xq[0][0];       // [4][6][16]
    float* redm = redc + 384;
#pragma unroll
    for (int j = 0; j < NDIL; ++j) {
        float c = cnt[j], m = mx[j];
        c += __shfl_xor(c, 16);  m = fmaxf(m, __shfl_xor(m, 16));
        c += __shfl_xor(c, 32);  m = fmaxf(m, __shfl_xor(m, 32));
        if (lane < 16) {
            redc[(wv * 6 + j) * 16 + lane] = c;
            redm[(wv * 6 + j) * 16 + lane] = m;
        }
    }
    __syncthreads();

    if (tid < 96) {
        const int jj = tid >> 4, s = tid & 15;
        if (s < 15) {
            float c = 0.0f, m = -INFINITY;
#pragma unroll
            for (int w = 0; w < 4; ++w) {
                c += redc[(w * 6 + jj) * 16 + s];
                m  = fmaxf(m, redm[(w * 6 + jj) * 16 + s]);
            }
            const int ks = s / 5, f = s % 5;
            const int gg = jj * 5 + f;
            const size_t base =
                ((((size_t)ks * N_SAMP + n) * NCHUNK + ch) * NFILT + gg) * 2;
            ws[base]     = c;
            ws[base + 1] = m;
        }
    }
}

// ---------------------------------------------------------------------------
// Reduce chunks -> feature value, then per-feature batch norm.
// ---------------------------------------------------------------------------
__global__ __launch_bounds__(512)
void rocket_finish(const float* __restrict__ ws, float* __restrict__ out)
{
    const int i = blockIdx.x;
    const int t = threadIdx.x;

    const int ks = i / 60;
    const int r  = i % 60;
    const int g  = r >> 1;
    const int m  = r & 1;

    const size_t base =
        ((((size_t)ks * N_SAMP + t) * NCHUNK) * NFILT + g) * 2 + m;

    float v;
    if (m) {
        v = -INFINITY;
#pragma unroll
        for (int c = 0; c < NCHUNK; ++c)
            v = fmaxf(v, ws[base + (size_t)c * NFILT * 2]);
    } else {
        v = 0.0f;
#pragma unroll
        for (int c = 0; c < NCHUNK; ++c)
            v += ws[base + (size_t)c * NFILT * 2];
        v *= (1.0f / (float)L_IN);
    }

    float s  = v;
    float sq = v * v;
#pragma unroll
    for (int off = 32; off; off >>= 1) {
        s  += __shfl_xor(s, off);
        sq += __shfl_xor(sq, off);
    }

    __shared__ float ss[8], sqq[8];
    const int lane = t & 63;
    const int wv   = t >> 6;
    if (lane == 0) { ss[wv] = s; sqq[wv] = sq; }
    __syncthreads();
    if (t == 0) {
        float S = 0.0f, Q = 0.0f;
#pragma unroll
        for (int w = 0; w < 8; ++w) { S += ss[w]; Q += sqq[w]; }
        ss[0] = S; sqq[0] = Q;
    }
    __syncthreads();

    const float mean = ss[0] * (1.0f / (float)N_SAMP);
    const float var  = sqq[0] * (1.0f / (float)N_SAMP) - mean * mean;
    out[t * NFEAT + i] = (v - mean) / sqrtf(var + EPSV);
}

// ---------------------------------------------------------------------------
extern "C" void kernel_launch(void* const* d_in, const int* in_sizes, int n_in,
                              void* d_out, int out_size, void* d_ws, size_t ws_size,
                              hipStream_t stream)
{
    const float* x   = (const float*)d_in[0];
    const float* W7  = (const float*)d_in[1];
    const float* b7  = (const float*)d_in[2];
    const float* W9  = (const float*)d_in[3];
    const float* b9  = (const float*)d_in[4];
    const float* W11 = (const float*)d_in[5];
    const float* b11 = (const float*)d_in[6];
    float* out = (float*)d_out;
    float* ws  = (float*)d_ws;                 // 1.47 MB partials + tables
    signed char* wc = (signed char*)(ws + WF_OFF);
    signed char* wd = wc + WTAB_B;
    float* bias_tab = (float*)(wd + WTAB_B);

    build_wb<<<5, 256, 0, stream>>>(W7, W9, W11, b7, b9, b11, wc, wd, bias_tab);

    dim3 grid(NCHUNK, N_SAMP);
    rocket_conv_i8<<<grid, 256, 0, stream>>>(x, wc, wd, bias_tab, ws);

    rocket_finish<<<NFEAT, 512, 0, stream>>>(ws, out);
}

// Round 8
// 814.213 us; speedup vs baseline: 1.3343x; 1.3343x over previous
//
#include <hip/hip_runtime.h>
#include <math.h>

#define N_SAMP 512
#define C_IN   12
#define L_IN   8192
#define NDIL   6
#define NFILT  30
#define NFEAT  180
#define NCHUNK 4
#define CHUNK  (L_IN / NCHUNK)   // 2048
#define EPSV   1e-5f

#define HALO   160               // 5 * max dilation(32)
#define TLC    512               // positions per stage tile
#define LWC    (TLC + 2*HALO)    // 832 rows
#define TILEB  (LWC * 16)        // 13312 bytes per (hi|lo) LDS part

// ws layout: [0, WF_OFF) float partials; then wc, wd (i8 frag tables), bias
#define WF_OFF (3 * N_SAMP * NCHUNK * NFILT * 2)   // 368640 floats
#define WTAB_B (NDIL * 3 * 64 * 16)                // 18432 bytes per table

typedef __attribute__((ext_vector_type(4))) int i32x4;

// XOR quad-swizzle: bijective involution on 16B cells, varies under row
// steps of 8/16/32 so all dilation strides spread across bank quads.
__device__ __forceinline__ int swz(int r) {
    return (r << 4) ^ (((r >> 3) & 7) << 4);
}

// ---------------------------------------------------------------------------
// Build i8 B-fragment tables: W = round(w*8192) = 256*C + D, C in [-32,32],
// D in [-128,127]. MFMA lane layout: k = q*16 + e -> (tap = mf*4+q, c = e).
// tap 11 (mf=2,q=3) is zero-weighted padding.
// ---------------------------------------------------------------------------
__global__ __launch_bounds__(256)
void build_wb(const float* __restrict__ W7, const float* __restrict__ W9,
              const float* __restrict__ W11, const float* __restrict__ b7,
              const float* __restrict__ b9, const float* __restrict__ b11,
              signed char* __restrict__ wc, signed char* __restrict__ wd,
              float* __restrict__ bias_tab)
{
    const int t = blockIdx.x * 256 + threadIdx.x;
    if (t < NDIL * 3 * 64) {
        const int j    = t / 192;
        const int mf   = (t / 64) % 3;
        const int lane = t % 64;
        const int col  = lane & 15;
        const int q    = lane >> 4;
        const int tap  = mf * 4 + q;
#pragma unroll
        for (int e = 0; e < 16; ++e) {
            float v = 0.0f;
            if (col < 15 && tap <= 10 && e < 12) {
                const int toff = tap - 5;
                if (col < 5) {
                    if (toff >= -3 && toff <= 3)
                        v = W7[((j * 5 + col) * 12 + e) * 7 + toff + 3];
                } else if (col < 10) {
                    if (toff >= -4 && toff <= 4)
                        v = W9[((j * 5 + col - 5) * 12 + e) * 9 + toff + 4];
                } else {
                    v = W11[((j * 5 + col - 10) * 12 + e) * 11 + toff + 5];
                }
            }
            const int W  = __float2int_rn(v * 8192.0f);
            const int C8 = (W + 128) >> 8;      // in [-32, 32]
            const int D8 = W - (C8 << 8);       // in [-128, 127]
            wc[(size_t)t * 16 + e] = (signed char)C8;
            wd[(size_t)t * 16 + e] = (signed char)D8;
        }
    } else if (t < NDIL * 3 * 64 + 96) {
        const int i = t - NDIL * 3 * 64;
        const int j = i / 16, s = i % 16;
        float b = 0.0f;
        if (s < 5)       b = b7 [j * 5 + s];
        else if (s < 10) b = b9 [j * 5 + s - 5];
        else if (s < 15) b = b11[j * 5 + s - 10];
        bias_tab[j * 16 + s] = b;
    }
}

// ---------------------------------------------------------------------------
// i8 MFMA conv, EXACT 4-term fixed-point product of quantized values:
//   X = round(x*4096) = 256A + B;  W = round(w*8192) = 256C + D
//   X*W = 65536*(A.C) + 256*(A.D + B.C) + B.D   -> /2^25
// Remaining error = input quantization only (sigma ~6e-4 per conv output).
// One (sample, 2048-chunk) per block, all 6 dilations, all 3 kernel sizes.
// Per 16-pos tile per dilation: 6 ds_read_b128 + 12 MFMA (K=64 = 4tap x 16c).
// NOTE: no min-occupancy attribute — launch_bounds(256,4) forced a 64-VGPR
// allocation and catastrophic scratch spills in rounds 2 and 7.
// ---------------------------------------------------------------------------
__global__ __launch_bounds__(256)
void rocket_conv_i8(const float* __restrict__ x,
                    const signed char* __restrict__ wc,
                    const signed char* __restrict__ wd,
                    const float* __restrict__ bias_tab,
                    float* __restrict__ ws)
{
    __shared__ __align__(16) signed char xq[2][TILEB];   // A | B, 26624 B

    const int ch  = blockIdx.x;
    const int n   = blockIdx.y;
    const int tid = threadIdx.x;
    const int lane = tid & 63, wv = tid >> 6;
    const int row_l = lane & 15, q = lane >> 4;
    const float* __restrict__ xrow = x + (size_t)n * C_IN * L_IN;
    const i32x4* __restrict__ wcv = (const i32x4*)wc;
    const i32x4* __restrict__ wdv = (const i32x4*)wd;

    float bcol[NDIL];
#pragma unroll
    for (int j = 0; j < NDIL; ++j) bcol[j] = bias_tab[j * 16 + row_l];

    float cnt[NDIL], mx[NDIL];
#pragma unroll
    for (int j = 0; j < NDIL; ++j) { cnt[j] = 0.0f; mx[j] = -INFINITY; }

    const float S0 = 1.0f / 512.0f;        // 65536 / 2^25
    const float S1 = 1.0f / 131072.0f;     // 256   / 2^25
    const float S2 = 1.0f / 33554432.0f;   // 1     / 2^25

    const int c0 = ch * CHUNK;
#pragma unroll 1
    for (int st = 0; st < CHUNK / TLC; ++st) {
        const int t0 = c0 + st * TLC;
        __syncthreads();
        // ---- stage: quantize x to (A,B) i8 pairs, swizzled 16B rows ----
#pragma unroll 1
        for (int r = tid; r < LWC; r += 256) {
            const int g = t0 - HALO + r;
            int h[4] = {0, 0, 0, 0}, l[4] = {0, 0, 0, 0};
            if ((unsigned)g < (unsigned)L_IN) {
#pragma unroll
                for (int c = 0; c < 12; ++c) {
                    const float xv = xrow[c * L_IN + g];
                    const int X  = __float2int_rn(xv * 4096.0f);
                    const int A8 = (X + 128) >> 8;     // [-91, 91]
                    const int B8 = X - (A8 << 8);      // [-128, 127]
                    h[c >> 2] |= (A8 & 255) << ((c & 3) * 8);
                    l[c >> 2] |= (B8 & 255) << ((c & 3) * 8);
                }
            }
            const int cell = swz(r);
            *(i32x4*)&xq[0][cell] = (i32x4){h[0], h[1], h[2], h[3]};
            *(i32x4*)&xq[1][cell] = (i32x4){l[0], l[1], l[2], l[3]};
        }
        __syncthreads();

        // ---- compute: 6 dilations x 8 pos-tiles/wave ----
#pragma unroll
        for (int j = 0; j < NDIL; ++j) {
            const int d = 1 << j;
            i32x4 C0 = wcv[(j * 3 + 0) * 64 + lane];
            i32x4 C1 = wcv[(j * 3 + 1) * 64 + lane];
            i32x4 C2 = wcv[(j * 3 + 2) * 64 + lane];
            i32x4 D0 = wdv[(j * 3 + 0) * 64 + lane];
            i32x4 D1 = wdv[(j * 3 + 1) * 64 + lane];
            i32x4 D2 = wdv[(j * 3 + 2) * 64 + lane];
            // per-lane A row offsets for taps {q, q+4, q+8} (tap 11 -> 0)
            const int r0 = HALO + wv * 128 + row_l + (q - 5) * d;
            const int r1 = HALO + wv * 128 + row_l + (q - 1) * d;
            const int r2 = HALO + wv * 128 + row_l +
                           ((q == 3) ? 0 : (q + 3) * d);
            const float bj = bcol[j];
#pragma unroll
            for (int t = 0; t < 8; ++t) {
                const int cell0 = swz(r0 + 16 * t);
                const int cell1 = swz(r1 + 16 * t);
                const int cell2 = swz(r2 + 16 * t);
                i32x4 a0 = {0, 0, 0, 0};   // A.C
                i32x4 a1 = {0, 0, 0, 0};   // A.D + B.C
                i32x4 a2 = {0, 0, 0, 0};   // B.D
                {
                    i32x4 ah = *(const i32x4*)&xq[0][cell0];
                    i32x4 al = *(const i32x4*)&xq[1][cell0];
                    a0 = __builtin_amdgcn_mfma_i32_16x16x64_i8(ah, C0, a0, 0, 0, 0);
                    a1 = __builtin_amdgcn_mfma_i32_16x16x64_i8(ah, D0, a1, 0, 0, 0);
                    a1 = __builtin_amdgcn_mfma_i32_16x16x64_i8(al, C0, a1, 0, 0, 0);
                    a2 = __builtin_amdgcn_mfma_i32_16x16x64_i8(al, D0, a2, 0, 0, 0);
                }
                {
                    i32x4 ah = *(const i32x4*)&xq[0][cell1];
                    i32x4 al = *(const i32x4*)&xq[1][cell1];
                    a0 = __builtin_amdgcn_mfma_i32_16x16x64_i8(ah, C1, a0, 0, 0, 0);
                    a1 = __builtin_amdgcn_mfma_i32_16x16x64_i8(ah, D1, a1, 0, 0, 0);
                    a1 = __builtin_amdgcn_mfma_i32_16x16x64_i8(al, C1, a1, 0, 0, 0);
                    a2 = __builtin_amdgcn_mfma_i32_16x16x64_i8(al, D1, a2, 0, 0, 0);
                }
                {
                    i32x4 ah = *(const i32x4*)&xq[0][cell2];
                    i32x4 al = *(const i32x4*)&xq[1][cell2];
                    a0 = __builtin_amdgcn_mfma_i32_16x16x64_i8(ah, C2, a0, 0, 0, 0);
                    a1 = __builtin_amdgcn_mfma_i32_16x16x64_i8(ah, D2, a1, 0, 0, 0);
                    a1 = __builtin_amdgcn_mfma_i32_16x16x64_i8(al, C2, a1, 0, 0, 0);
                    a2 = __builtin_amdgcn_mfma_i32_16x16x64_i8(al, D2, a2, 0, 0, 0);
                }
#pragma unroll
                for (int i = 0; i < 4; ++i) {
                    const float out = bj + (float)a0[i] * S0
                                         + (float)a1[i] * S1
                                         + (float)a2[i] * S2;
                    cnt[j] += (out > 0.0f) ? 1.0f : 0.0f;
                    mx[j]   = fmaxf(mx[j], out);
                }
            }
        }
    }

    // ---- reduce: lanes {s, s+16, s+32, s+48} hold same filter col s ----
    __syncthreads();                       // xq dead; alias reduction scratch
    float* redc = (float*)&xq[0][0];       // [4][6][16]
    float* redm = redc + 384;
#pragma unroll
    for (int j = 0; j < NDIL; ++j) {
        float c = cnt[j], m = mx[j];
        c += __shfl_xor(c, 16);  m = fmaxf(m, __shfl_xor(m, 16));
        c += __shfl_xor(c, 32);  m = fmaxf(m, __shfl_xor(m, 32));
        if (lane < 16) {
            redc[(wv * 6 + j) * 16 + lane] = c;
            redm[(wv * 6 + j) * 16 + lane] = m;
        }
    }
    __syncthreads();

    if (tid < 96) {
        const int jj = tid >> 4, s = tid & 15;
        if (s < 15) {
            float c = 0.0f, m = -INFINITY;
#pragma unroll
            for (int w = 0; w < 4; ++w) {
                c += redc[(w * 6 + jj) * 16 + s];
                m  = fmaxf(m, redm[(w * 6 + jj) * 16 + s]);
            }
            const int ks = s / 5, f = s % 5;
            const int gg = jj * 5 + f;
            const size_t base =
                ((((size_t)ks * N_SAMP + n) * NCHUNK + ch) * NFILT + gg) * 2;
            ws[base]     = c;
            ws[base + 1] = m;
        }
    }
}

// ---------------------------------------------------------------------------
// Reduce chunks -> feature value, then per-feature batch norm.
// ---------------------------------------------------------------------------
__global__ __launch_bounds__(512)
void rocket_finish(const float* __restrict__ ws, float* __restrict__ out)
{
    const int i = blockIdx.x;
    const int t = threadIdx.x;

    const int ks = i / 60;
    const int r  = i % 60;
    const int g  = r >> 1;
    const int m  = r & 1;

    const size_t base =
        ((((size_t)ks * N_SAMP + t) * NCHUNK) * NFILT + g) * 2 + m;

    float v;
    if (m) {
        v = -INFINITY;
#pragma unroll
        for (int c = 0; c < NCHUNK; ++c)
            v = fmaxf(v, ws[base + (size_t)c * NFILT * 2]);
    } else {
        v = 0.0f;
#pragma unroll
        for (int c = 0; c < NCHUNK; ++c)
            v += ws[base + (size_t)c * NFILT * 2];
        v *= (1.0f / (float)L_IN);
    }

    float s  = v;
    float sq = v * v;
#pragma unroll
    for (int off = 32; off; off >>= 1) {
        s  += __shfl_xor(s, off);
        sq += __shfl_xor(sq, off);
    }

    __shared__ float ss[8], sqq[8];
    const int lane = t & 63;
    const int wv   = t >> 6;
    if (lane == 0) { ss[wv] = s; sqq[wv] = sq; }
    __syncthreads();
    if (t == 0) {
        float S = 0.0f, Q = 0.0f;
#pragma unroll
        for (int w = 0; w < 8; ++w) { S += ss[w]; Q += sqq[w]; }
        ss[0] = S; sqq[0] = Q;
    }
    __syncthreads();

    const float mean = ss[0] * (1.0f / (float)N_SAMP);
    const float var  = sqq[0] * (1.0f / (float)N_SAMP) - mean * mean;
    out[t * NFEAT + i] = (v - mean) / sqrtf(var + EPSV);
}

// ---------------------------------------------------------------------------
extern "C" void kernel_launch(void* const* d_in, const int* in_sizes, int n_in,
                              void* d_out, int out_size, void* d_ws, size_t ws_size,
                              hipStream_t stream)
{
    const float* x   = (const float*)d_in[0];
    const float* W7  = (const float*)d_in[1];
    const float* b7  = (const float*)d_in[2];
    const float* W9  = (const float*)d_in[3];
    const float* b9  = (const float*)d_in[4];
    const float* W11 = (const float*)d_in[5];
    const float* b11 = (const float*)d_in[6];
    float* out = (float*)d_out;
    float* ws  = (float*)d_ws;                 // 1.47 MB partials + tables
    signed char* wc = (signed char*)(ws + WF_OFF);
    signed char* wd = wc + WTAB_B;
    float* bias_tab = (float*)(wd + WTAB_B);

    build_wb<<<5, 256, 0, stream>>>(W7, W9, W11, b7, b9, b11, wc, wd, bias_tab);

    dim3 grid(NCHUNK, N_SAMP);
    rocket_conv_i8<<<grid, 256, 0, stream>>>(x, wc, wd, bias_tab, ws);

    rocket_finish<<<NFEAT, 512, 0, stream>>>(ws, out);
}

// Round 9
// 286.185 us; speedup vs baseline: 3.7961x; 2.8451x over previous
//
#include <hip/hip_runtime.h>
#include <math.h>
#include <limits.h>

#define N_SAMP 512
#define C_IN   12
#define L_IN   8192
#define NDIL   6
#define NFILT  30
#define NFEAT  180
#define NCHUNK 4
#define CHUNK  (L_IN / NCHUNK)   // 2048
#define EPSV   1e-5f

#define HALO   160               // 5 * max dilation(32)
#define TLC    512               // positions per stage tile
#define LWC    (TLC + 2*HALO)    // 832 rows
#define TILEB  (LWC * 16)        // 13312 bytes per (A|B) LDS part

// ws layout: [0, WF_OFF) float partials; then wc, wd (i8 frag tables), bias
#define WF_OFF (3 * N_SAMP * NCHUNK * NFILT * 2)   // 368640 floats
#define WTAB_B (NDIL * 3 * 64 * 16)                // 18432 bytes per table

typedef __attribute__((ext_vector_type(4))) int i32x4;

// XOR swizzle on 16B cells. Key varies under row steps 8,16,32,64,128,256
// (all tap strides d..4d for d=1..32), so every wave read spreads across
// banks; bijective (key depends only on r>>3, XOR within 8-row groups).
__device__ __forceinline__ int swz(int r) {
    return (r << 4) ^ ((((r >> 3) ^ (r >> 6)) & 7) << 4);
}

// ---------------------------------------------------------------------------
// Build i8 B-fragment tables: W = round(w*8192) = 256*C + D, C in [-32,32],
// D in [-128,127]. MFMA lane layout: k = q*16 + e -> (tap = mf*4+q, c = e).
// tap 11 (mf=2,q=3) is zero-weighted padding.
// ---------------------------------------------------------------------------
__global__ __launch_bounds__(256)
void build_wb(const float* __restrict__ W7, const float* __restrict__ W9,
              const float* __restrict__ W11, const float* __restrict__ b7,
              const float* __restrict__ b9, const float* __restrict__ b11,
              signed char* __restrict__ wc, signed char* __restrict__ wd,
              float* __restrict__ bias_tab)
{
    const int t = blockIdx.x * 256 + threadIdx.x;
    if (t < NDIL * 3 * 64) {
        const int j    = t / 192;
        const int mf   = (t / 64) % 3;
        const int lane = t % 64;
        const int col  = lane & 15;
        const int q    = lane >> 4;
        const int tap  = mf * 4 + q;
#pragma unroll
        for (int e = 0; e < 16; ++e) {
            float v = 0.0f;
            if (col < 15 && tap <= 10 && e < 12) {
                const int toff = tap - 5;
                if (col < 5) {
                    if (toff >= -3 && toff <= 3)
                        v = W7[((j * 5 + col) * 12 + e) * 7 + toff + 3];
                } else if (col < 10) {
                    if (toff >= -4 && toff <= 4)
                        v = W9[((j * 5 + col - 5) * 12 + e) * 9 + toff + 4];
                } else {
                    v = W11[((j * 5 + col - 10) * 12 + e) * 11 + toff + 5];
                }
            }
            const int W  = __float2int_rn(v * 8192.0f);
            const int C8 = (W + 128) >> 8;      // in [-32, 32]
            const int D8 = W - (C8 << 8);       // in [-128, 127]
            wc[(size_t)t * 16 + e] = (signed char)C8;
            wd[(size_t)t * 16 + e] = (signed char)D8;
        }
    } else if (t < NDIL * 3 * 64 + 96) {
        const int i = t - NDIL * 3 * 64;
        const int j = i / 16, s = i % 16;
        float b = 0.0f;
        if (s < 5)       b = b7 [j * 5 + s];
        else if (s < 10) b = b9 [j * 5 + s - 5];
        else if (s < 15) b = b11[j * 5 + s - 10];
        bias_tab[j * 16 + s] = b;
    }
}

// ---------------------------------------------------------------------------
// i8 MFMA conv, EXACT 4-term fixed-point product:
//   X = round(x*4096) = 256A + B;  W = round(w*8192) = 256C + D
//   X*W = 65536*(A.C) + 256*(A.D + B.C) + B.D  (exact in wrapping i32, since
//   |conv|*2^25 < 2^31). PPV/max done in the integer domain.
// Dilation loop ROLLED (one dilation's frags live -> low VGPR, round-8 fix);
// per-dilation stats flushed to dedicated LDS scratch each stage (no runtime-
// indexed register arrays).
// NOTE: no min-occupancy launch_bounds arg — (256,4) caused 64-VGPR scratch
// spills in rounds 2 and 7.
// ---------------------------------------------------------------------------
__global__ __launch_bounds__(256)
void rocket_conv_i8(const float* __restrict__ x,
                    const signed char* __restrict__ wc,
                    const signed char* __restrict__ wd,
                    const float* __restrict__ bias_tab,
                    float* __restrict__ ws)
{
    __shared__ __align__(16) signed char xq[2][TILEB];   // A | B, 26624 B
    __shared__ int redcnt[4 * NDIL * 16];                // [wv][j][col]
    __shared__ int redmx [4 * NDIL * 16];

    const int ch  = blockIdx.x;
    const int n   = blockIdx.y;
    const int tid = threadIdx.x;
    const int lane = tid & 63, wv = tid >> 6;
    const int row_l = lane & 15, q = lane >> 4;
    const float* __restrict__ xrow = x + (size_t)n * C_IN * L_IN;
    const i32x4* __restrict__ wcv = (const i32x4*)wc;
    const i32x4* __restrict__ wdv = (const i32x4*)wd;

    for (int i = tid; i < 4 * NDIL * 16; i += 256) {
        redcnt[i] = 0;
        redmx[i]  = INT_MIN;
    }

    const int c0 = ch * CHUNK;
#pragma unroll 1
    for (int st = 0; st < CHUNK / TLC; ++st) {
        const int t0 = c0 + st * TLC;
        __syncthreads();   // also covers the redcnt/redmx init on st==0
        // ---- stage: quantize x to (A,B) i8 pairs, swizzled 16B rows ----
#pragma unroll 1
        for (int r = tid; r < LWC; r += 256) {
            const int g = t0 - HALO + r;
            int h[4] = {0, 0, 0, 0}, l[4] = {0, 0, 0, 0};
            if ((unsigned)g < (unsigned)L_IN) {
#pragma unroll
                for (int c = 0; c < 12; ++c) {
                    const float xv = xrow[c * L_IN + g];
                    const int X  = __float2int_rn(xv * 4096.0f);
                    const int A8 = (X + 128) >> 8;     // [-91, 91]
                    const int B8 = X - (A8 << 8);      // [-128, 127]
                    h[c >> 2] |= (A8 & 255) << ((c & 3) * 8);
                    l[c >> 2] |= (B8 & 255) << ((c & 3) * 8);
                }
            }
            const int cell = swz(r);
            *(i32x4*)&xq[0][cell] = (i32x4){h[0], h[1], h[2], h[3]};
            *(i32x4*)&xq[1][cell] = (i32x4){l[0], l[1], l[2], l[3]};
        }
        __syncthreads();

        // ---- compute: dilations ROLLED, 8 pos-tiles/wave each ----
#pragma unroll 1
        for (int j = 0; j < NDIL; ++j) {
            const int d = 1 << j;
            const i32x4 C0 = wcv[(j * 3 + 0) * 64 + lane];
            const i32x4 C1 = wcv[(j * 3 + 1) * 64 + lane];
            const i32x4 C2 = wcv[(j * 3 + 2) * 64 + lane];
            const i32x4 D0 = wdv[(j * 3 + 0) * 64 + lane];
            const i32x4 D1 = wdv[(j * 3 + 1) * 64 + lane];
            const i32x4 D2 = wdv[(j * 3 + 2) * 64 + lane];
            // integer threshold: out>0  <=>  tot > -bias*2^25
            const float bj = bias_tab[j * 16 + row_l];
            const int tj = (int)floorf(bj * -33554432.0f);
            // per-lane A row offsets for taps {q, q+4, q+8} (tap 11 -> 0)
            const int r0 = HALO + wv * 128 + row_l + (q - 5) * d;
            const int r1 = HALO + wv * 128 + row_l + (q - 1) * d;
            const int r2 = HALO + wv * 128 + row_l +
                           ((q == 3) ? 0 : (q + 3) * d);

            int cnt_i = 0, mx_i = INT_MIN;
#pragma unroll
            for (int t = 0; t < 8; ++t) {
                const int cell0 = swz(r0 + 16 * t);
                const int cell1 = swz(r1 + 16 * t);
                const int cell2 = swz(r2 + 16 * t);
                i32x4 a0 = {0, 0, 0, 0};   // A.C
                i32x4 a1 = {0, 0, 0, 0};   // A.D + B.C
                i32x4 a2 = {0, 0, 0, 0};   // B.D
                {
                    i32x4 ah = *(const i32x4*)&xq[0][cell0];
                    i32x4 al = *(const i32x4*)&xq[1][cell0];
                    a0 = __builtin_amdgcn_mfma_i32_16x16x64_i8(ah, C0, a0, 0, 0, 0);
                    a1 = __builtin_amdgcn_mfma_i32_16x16x64_i8(ah, D0, a1, 0, 0, 0);
                    a1 = __builtin_amdgcn_mfma_i32_16x16x64_i8(al, C0, a1, 0, 0, 0);
                    a2 = __builtin_amdgcn_mfma_i32_16x16x64_i8(al, D0, a2, 0, 0, 0);
                }
                {
                    i32x4 ah = *(const i32x4*)&xq[0][cell1];
                    i32x4 al = *(const i32x4*)&xq[1][cell1];
                    a0 = __builtin_amdgcn_mfma_i32_16x16x64_i8(ah, C1, a0, 0, 0, 0);
                    a1 = __builtin_amdgcn_mfma_i32_16x16x64_i8(ah, D1, a1, 0, 0, 0);
                    a1 = __builtin_amdgcn_mfma_i32_16x16x64_i8(al, C1, a1, 0, 0, 0);
                    a2 = __builtin_amdgcn_mfma_i32_16x16x64_i8(al, D1, a2, 0, 0, 0);
                }
                {
                    i32x4 ah = *(const i32x4*)&xq[0][cell2];
                    i32x4 al = *(const i32x4*)&xq[1][cell2];
                    a0 = __builtin_amdgcn_mfma_i32_16x16x64_i8(ah, C2, a0, 0, 0, 0);
                    a1 = __builtin_amdgcn_mfma_i32_16x16x64_i8(ah, D2, a1, 0, 0, 0);
                    a1 = __builtin_amdgcn_mfma_i32_16x16x64_i8(al, C2, a1, 0, 0, 0);
                    a2 = __builtin_amdgcn_mfma_i32_16x16x64_i8(al, D2, a2, 0, 0, 0);
                }
#pragma unroll
                for (int i = 0; i < 4; ++i) {
                    const int tot = (a0[i] << 16) + (a1[i] << 8) + a2[i];
                    cnt_i += (tot > tj) ? 1 : 0;
                    mx_i   = (tot > mx_i) ? tot : mx_i;
                }
            }

            // flush this dilation's stats (per-wave LDS slice, no races)
            cnt_i += __shfl_xor(cnt_i, 16);
            cnt_i += __shfl_xor(cnt_i, 32);
            {
                int o = __shfl_xor(mx_i, 16);  mx_i = (o > mx_i) ? o : mx_i;
                o     = __shfl_xor(mx_i, 32);  mx_i = (o > mx_i) ? o : mx_i;
            }
            if (lane < 16) {
                const int idx = (wv * NDIL + j) * 16 + lane;
                redcnt[idx] += cnt_i;
                if (mx_i > redmx[idx]) redmx[idx] = mx_i;
            }
        }
    }

    __syncthreads();
    if (tid < 96) {
        const int jj = tid >> 4, s = tid & 15;
        if (s < 15) {
            int c = 0, m = INT_MIN;
#pragma unroll
            for (int w = 0; w < 4; ++w) {
                c += redcnt[(w * NDIL + jj) * 16 + s];
                const int v = redmx[(w * NDIL + jj) * 16 + s];
                m = (v > m) ? v : m;
            }
            const float bj = bias_tab[jj * 16 + s];
            const int ks = s / 5, f = s % 5;
            const int gg = jj * 5 + f;
            const size_t base =
                ((((size_t)ks * N_SAMP + n) * NCHUNK + ch) * NFILT + gg) * 2;
            ws[base]     = (float)c;
            ws[base + 1] = bj + (float)m * 2.9802322387695312e-8f; // 2^-25
        }
    }
}

// ---------------------------------------------------------------------------
// Reduce chunks -> feature value, then per-feature batch norm.
// ---------------------------------------------------------------------------
__global__ __launch_bounds__(512)
void rocket_finish(const float* __restrict__ ws, float* __restrict__ out)
{
    const int i = blockIdx.x;
    const int t = threadIdx.x;

    const int ks = i / 60;
    const int r  = i % 60;
    const int g  = r >> 1;
    const int m  = r & 1;

    const size_t base =
        ((((size_t)ks * N_SAMP + t) * NCHUNK) * NFILT + g) * 2 + m;

    float v;
    if (m) {
        v = -INFINITY;
#pragma unroll
        for (int c = 0; c < NCHUNK; ++c)
            v = fmaxf(v, ws[base + (size_t)c * NFILT * 2]);
    } else {
        v = 0.0f;
#pragma unroll
        for (int c = 0; c < NCHUNK; ++c)
            v += ws[base + (size_t)c * NFILT * 2];
        v *= (1.0f / (float)L_IN);
    }

    float s  = v;
    float sq = v * v;
#pragma unroll
    for (int off = 32; off; off >>= 1) {
        s  += __shfl_xor(s, off);
        sq += __shfl_xor(sq, off);
    }

    __shared__ float ss[8], sqq[8];
    const int lane = t & 63;
    const int wv   = t >> 6;
    if (lane == 0) { ss[wv] = s; sqq[wv] = sq; }
    __syncthreads();
    if (t == 0) {
        float S = 0.0f, Q = 0.0f;
#pragma unroll
        for (int w = 0; w < 8; ++w) { S += ss[w]; Q += sqq[w]; }
        ss[0] = S; sqq[0] = Q;
    }
    __syncthreads();

    const float mean = ss[0] * (1.0f / (float)N_SAMP);
    const float var  = sqq[0] * (1.0f / (float)N_SAMP) - mean * mean;
    out[t * NFEAT + i] = (v - mean) / sqrtf(var + EPSV);
}

// ---------------------------------------------------------------------------
extern "C" void kernel_launch(void* const* d_in, const int* in_sizes, int n_in,
                              void* d_out, int out_size, void* d_ws, size_t ws_size,
                              hipStream_t stream)
{
    const float* x   = (const float*)d_in[0];
    const float* W7  = (const float*)d_in[1];
    const float* b7  = (const float*)d_in[2];
    const float* W9  = (const float*)d_in[3];
    const float* b9  = (const float*)d_in[4];
    const float* W11 = (const float*)d_in[5];
    const float* b11 = (const float*)d_in[6];
    float* out = (float*)d_out;
    float* ws  = (float*)d_ws;                 // 1.47 MB partials + tables
    signed char* wc = (signed char*)(ws + WF_OFF);
    signed char* wd = wc + WTAB_B;
    float* bias_tab = (float*)(wd + WTAB_B);

    build_wb<<<5, 256, 0, stream>>>(W7, W9, W11, b7, b9, b11, wc, wd, bias_tab);

    dim3 grid(NCHUNK, N_SAMP);
    rocket_conv_i8<<<grid, 256, 0, stream>>>(x, wc, wd, bias_tab, ws);

    rocket_finish<<<NFEAT, 512, 0, stream>>>(ws, out);
}